// Round 9
// baseline (875.747 us; speedup 1.0000x reference)
//
#include <hip/hip_runtime.h>
#include <hip/hip_fp16.h>
#include <stdint.h>

typedef _Float16 f16;
typedef _Float16 f16x8 __attribute__((ext_vector_type(8)));
typedef float f32x4 __attribute__((ext_vector_type(4)));

#define NB 32768      // batch
#define LAYERS 6
#define AK 160        // HALF + COND
#define HID 1024

// async global->LDS, 16B per lane. LDS dest is wave-uniform base + lane*16.
__device__ __forceinline__ void async_copy16(const void* g, void* l) {
  __builtin_amdgcn_global_load_lds(
      (const __attribute__((address_space(1))) void*)g,
      (__attribute__((address_space(3))) void*)l, 16, 0, 0);
}

// ---------------------------------------------------------------------------
// Fused prep: one kernel replaces prep_batch + 3 wtrans launches.
//  blocks [0, 2048):        z = T, log_det = 0, A = [f16(T[:,32:]) | f16(cond)]
//  blocks [2048, 2336):     W1 transpose  (16 x 3 x 6 tiles,  K=160,  N=1024)
//  blocks [2336, 3872):     W2 transpose  (16 x 16 x 6 tiles, K=1024, N=1024)
//  blocks [3872, 3968):     W3 transpose  (1 x 16 x 6 tiles,  K=1024, N=64)
// Transpose: 64x64 LDS tile, coalesced reads AND writes, f32 -> f16.
// ---------------------------------------------------------------------------
__device__ __forceinline__ void wtrans_tile(const float* __restrict__ W,
                                            f16* __restrict__ Wt,
                                            const int K_, const int N_,
                                            const int bx, const int by,
                                            const int bz, float (*t)[65])
{
  const long off = (long)bz * K_ * N_;
  const float* Wl = W + off;
  f16* Wtl = Wt + off;
  const int k0 = by * 64, n0 = bx * 64;
  const int tx = threadIdx.x & 63, ty4 = threadIdx.x >> 6;
#pragma unroll
  for (int r = ty4; r < 64; r += 4) {
    const int k = k0 + r;
    if (k < K_) t[r][tx] = Wl[(long)k * N_ + n0 + tx];
  }
  __syncthreads();
  const int k = k0 + tx;
  if (k < K_) {
#pragma unroll
    for (int r = ty4; r < 64; r += 4) {
      const int n = n0 + r;
      Wtl[(long)n * K_ + k] = (f16)t[tx][r];
    }
  }
}

__global__ void prep_all(const float* __restrict__ T, const float* __restrict__ cond,
                         const float* __restrict__ W1, const float* __restrict__ W2,
                         const float* __restrict__ W3,
                         float* __restrict__ z, float* __restrict__ ld,
                         f16* __restrict__ A,
                         f16* __restrict__ W1t, f16* __restrict__ W2t,
                         f16* __restrict__ W3t)
{
  __shared__ float t[64][65];
  const int b = blockIdx.x;
  if (b < 2048) {
    const int S1 = NB * 64;
    const int S2 = S1 + NB;
    const int S3 = S2 + NB * 32;
    const int S4 = S3 + NB * 128;
    for (int i = b * blockDim.x + threadIdx.x; i < S4; i += 2048 * blockDim.x) {
      if (i < S1) {
        z[i] = T[i];
      } else if (i < S2) {
        ld[i - S1] = 0.0f;
      } else if (i < S3) {
        int r = i - S2;
        int row = r >> 5, j = r & 31;
        A[(size_t)row * AK + j] = (f16)T[row * 64 + 32 + j];
      } else {
        int r = i - S3;
        int row = r >> 7, j = r & 127;
        A[(size_t)row * AK + 32 + j] = (f16)cond[r];
      }
    }
  } else if (b < 2048 + 288) {
    const int l = b - 2048;                      // 16 x 3 x 6
    wtrans_tile(W1, W1t, AK, 1024, l % 16, (l / 16) % 3, l / 48, t);
  } else if (b < 2048 + 288 + 1536) {
    const int l = b - (2048 + 288);              // 16 x 16 x 6
    wtrans_tile(W2, W2t, HID, 1024, l % 16, (l / 16) % 16, l / 256, t);
  } else {
    const int l = b - (2048 + 288 + 1536);       // 1 x 16 x 6
    wtrans_tile(W3, W3t, HID, 64, 0, l % 16, l / 16, t);
  }
}

// ---------------------------------------------------------------------------
// GEMM1 (K=160): C[M x 1024] = relu(A[M x 160] @ W1t^T + b1), C in f16.
// Entire 128x160 A-tile and B-tile staged in LDS (80 KB, 2 blocks/CU),
// ONE barrier, then 80 MFMA straight. XOR bank swizzle as gemm12.
// ---------------------------------------------------------------------------
__global__ __launch_bounds__(256, 2)
void gemm1_full(const f16* __restrict__ A,
                const f16* __restrict__ Wt,       // 1024 x 160
                const float* __restrict__ bias,
                f16* __restrict__ C)
{
  __shared__ __align__(16) f16 As[128 * 160];     // 40 KB
  __shared__ __align__(16) f16 Bs[128 * 160];     // 40 KB
  const int tid  = threadIdx.x;
  const int lane = tid & 63;
  const int wave = tid >> 6;
  const int c15  = lane & 15;
  const int quad = lane >> 4;
  const int wm = (wave & 1) * 64;
  const int wn = (wave >> 1) * 64;

  const int b = blockIdx.x;
  const int x = b & 7, i = b >> 3;
  const long rowStart = (long)(x * 32 + (i >> 3)) * 128;
  const long colStart = (long)(i & 7) * 128;

  const f16* Ab = A  + rowStart * AK;
  const f16* Bb = Wt + colStart * AK;

  // stage both tiles fully: 2560 chunks each = 10 issues of 256.
  // slot f holds global chunk (f%20)^((row>>1)&3) of row f/20.
#pragma unroll
  for (int it = 0; it < 10; ++it) {
    const int f = it * 256 + tid;
    const int row = f / 20;
    const int ch  = f - row * 20;
    const int chs = ch ^ ((row >> 1) & 3);
    async_copy16(Ab + (long)row * AK + chs * 8, &As[0] + (long)f * 8);
    async_copy16(Bb + (long)row * AK + chs * 8, &Bs[0] + (long)f * 8);
  }
  __syncthreads();   // single barrier; compiler drains vmcnt(0) here

  f32x4 acc[4][4] = {};
#pragma unroll
  for (int kt = 0; kt < 5; ++kt) {
    f16x8 a[4], bf[4];
#pragma unroll
    for (int mi = 0; mi < 4; ++mi) {
      const int R = wm + mi * 16 + c15;
      a[mi] = *(const f16x8*)&As[(R * 20 + kt * 4 + (quad ^ ((R >> 1) & 3))) * 8];
    }
#pragma unroll
    for (int ni = 0; ni < 4; ++ni) {
      const int R = wn + ni * 16 + c15;
      bf[ni] = *(const f16x8*)&Bs[(R * 20 + kt * 4 + (quad ^ ((R >> 1) & 3))) * 8];
    }
#pragma unroll
    for (int mi = 0; mi < 4; ++mi)
#pragma unroll
      for (int ni = 0; ni < 4; ++ni)
        acc[mi][ni] = __builtin_amdgcn_mfma_f32_16x16x32_f16(
            a[mi], bf[ni], acc[mi][ni], 0, 0, 0);
  }

#pragma unroll
  for (int ni = 0; ni < 4; ++ni) {
    const long gn = colStart + wn + ni * 16 + c15;
    const float bv = bias[gn];
#pragma unroll
    for (int mi = 0; mi < 4; ++mi) {
#pragma unroll
      for (int r = 0; r < 4; ++r) {
        const long gm = rowStart + wm + mi * 16 + quad * 4 + r;
        float v = acc[mi][ni][r] + bv;
        v = fmaxf(v, 0.0f);
        C[gm * HID + gn] = (f16)v;
      }
    }
  }
}

// ---------------------------------------------------------------------------
// GEMM2 (K=1024): 128x128 block tile, BK=32, 4 waves, wave-tile 64x64.
// R9: __launch_bounds__(256,4) -> 4 blocks/CU (was 3). Resources fit:
// ~120 unified regs <= 128/wave, 4 x 32 KB = 128 KB LDS <= 160. The extra
// resident block is one more independent compute phase overlaying each
// barrier drain (R3 vs R7 showed the plateau is drain-coverage-bound, not
// LDS-BW-bound). A,B LDS dbuf; ONE barrier/k-step; XOR swizzle (0 conflicts).
// ---------------------------------------------------------------------------
__global__ __launch_bounds__(256, 4)
void gemm12(const f16* __restrict__ A, const int K,
            const f16* __restrict__ Wt,
            const float* __restrict__ bias,
            f16* __restrict__ C)
{
  __shared__ __align__(16) f16 As[2][128 * 32];
  __shared__ __align__(16) f16 Bs[2][128 * 32];
  const int tid  = threadIdx.x;
  const int wave = tid >> 6;
  const int lane = tid & 63;
  const int c15  = lane & 15;
  const int quad = lane >> 4;
  const int wm = (wave & 1) * 64;
  const int wn = (wave >> 1) * 64;

  const int b = blockIdx.x;
  const int x = b & 7, i = b >> 3;
  const long rowStart = (long)(x * 32 + (i >> 3)) * 128;
  const long colStart = (long)(i & 7) * 128;

  const f16* Ab = A  + rowStart * K;
  const f16* Bb = Wt + colStart * K;

  const int ra  = tid >> 2;
  const int kca = (((tid & 3) ^ ((ra >> 1) & 3))) * 8;

  f32x4 acc[4][4] = {};
  const int nK = K >> 5;

  auto stage = [&](int kt, int sel) {
    const long ko = (long)kt * 32;
    f16* as = &As[sel][0];
    f16* bs = &Bs[sel][0];
#pragma unroll
    for (int q = 0; q < 2; ++q)
      async_copy16(Ab + (long)(q * 64 + ra) * K + ko + kca,
                   as + (q * 256 + wave * 64) * 8);
#pragma unroll
    for (int q = 0; q < 2; ++q)
      async_copy16(Bb + (long)(q * 64 + ra) * K + ko + kca,
                   bs + (q * 256 + wave * 64) * 8);
  };

  stage(0, 0);
  for (int kt = 0; kt < nK; ++kt) {
    __syncthreads();
    if (kt + 1 < nK) stage(kt + 1, (kt + 1) & 1);
    const f16* as = &As[kt & 1][0];
    const f16* bs = &Bs[kt & 1][0];

    f16x8 a[4], bf[4];
#pragma unroll
    for (int mi = 0; mi < 4; ++mi) {
      const int R = wm + mi * 16 + c15;
      a[mi] = *(const f16x8*)&as[R * 32 + ((quad ^ ((R >> 1) & 3)) << 3)];
    }
#pragma unroll
    for (int ni = 0; ni < 4; ++ni) {
      const int R = wn + ni * 16 + c15;
      bf[ni] = *(const f16x8*)&bs[R * 32 + ((quad ^ ((R >> 1) & 3)) << 3)];
    }
#pragma unroll
    for (int mi = 0; mi < 4; ++mi)
#pragma unroll
      for (int ni = 0; ni < 4; ++ni)
        acc[mi][ni] = __builtin_amdgcn_mfma_f32_16x16x32_f16(
            a[mi], bf[ni], acc[mi][ni], 0, 0, 0);
  }

#pragma unroll
  for (int ni = 0; ni < 4; ++ni) {
    const long gn = colStart + wn + ni * 16 + c15;
    const float bv = bias[gn];
#pragma unroll
    for (int mi = 0; mi < 4; ++mi) {
#pragma unroll
      for (int r = 0; r < 4; ++r) {
        const long gm = rowStart + wm + mi * 16 + quad * 4 + r;
        float v = acc[mi][ni][r] + bv;
        v = fmaxf(v, 0.0f);
        C[gm * HID + gn] = (f16)v;
      }
    }
  }
}

// ---------------------------------------------------------------------------
// GEMM3 (N=64) + coupling epilogue. BM=64, grid 512 -> 2 blocks/CU.
// 4 waves x wave-tile 16x64. LDS dbuf 2 x 8 KB, 1 barrier/step, XOR swizzle.
// s-col j and t-col j+32 share lane & reg slot -> no shuffles.
// Writes y to z (fp32, in d_out) and to Anext[:, :32] (f16, next layer input).
// ---------------------------------------------------------------------------
__global__ __launch_bounds__(256, 4)
void gemm3_coupling(const f16* __restrict__ X2, const f16* __restrict__ W3t,
                    const float* __restrict__ b3, float* __restrict__ z,
                    float* __restrict__ log_det, f16* __restrict__ Anext,
                    const int maskoff)
{
  __shared__ __align__(16) f16 As[2][64 * 32];
  __shared__ __align__(16) f16 Bs[2][64 * 32];
  const int tid = threadIdx.x;
  const int wave = tid >> 6, lane = tid & 63;
  const int c15 = lane & 15, quad = lane >> 4;
  const int wm = wave * 16;
  const long rowStart = (long)blockIdx.x * 64;

  const f16* Ab = X2 + rowStart * HID;
  const int ra  = tid >> 2;                        // 0..63
  const int kca = (((tid & 3) ^ ((ra >> 1) & 3))) * 8;

  f32x4 acc[4] = {};

  auto stage = [&](int kt, int sel) {
    const long ko = (long)kt * 32;
    async_copy16(Ab + (long)ra * HID + ko + kca,
                 &As[sel][0] + (wave * 64) * 8);
    async_copy16(W3t + (long)ra * HID + ko + kca,
                 &Bs[sel][0] + (wave * 64) * 8);
  };

  stage(0, 0);
  for (int kt = 0; kt < 32; ++kt) {
    __syncthreads();
    if (kt + 1 < 32) stage(kt + 1, (kt + 1) & 1);
    const f16* as = &As[kt & 1][0];
    const f16* bs = &Bs[kt & 1][0];

    const int Ra = wm + c15;
    f16x8 a = *(const f16x8*)&as[Ra * 32 + ((quad ^ ((Ra >> 1) & 3)) << 3)];
    f16x8 bf[4];
#pragma unroll
    for (int ni = 0; ni < 4; ++ni) {
      const int R = ni * 16 + c15;
      bf[ni] = *(const f16x8*)&bs[R * 32 + ((quad ^ ((R >> 1) & 3)) << 3)];
    }
#pragma unroll
    for (int ni = 0; ni < 4; ++ni)
      acc[ni] = __builtin_amdgcn_mfma_f32_16x16x32_f16(a, bf[ni], acc[ni], 0, 0, 0);
  }

  float sp[4] = {0.0f, 0.0f, 0.0f, 0.0f};
#pragma unroll
  for (int ni = 0; ni < 2; ++ni) {
    const int j = ni * 16 + c15;          // s-column 0..31
    const float bs = b3[j];
    const float bt = b3[32 + j];
#pragma unroll
    for (int r = 0; r < 4; ++r) {
      const long gm = rowStart + wm + quad * 4 + r;
      const float sv = acc[ni][r] + bs;
      const float e2 = __expf(2.0f * sv);            // tanh via exp
      const float s  = 1.0f - 2.0f / (e2 + 1.0f);
      const float tv = acc[ni + 2][r] + bt;
      const float m  = z[gm * 64 + maskoff + j];
      const float y  = fmaf(m, __expf(s), tv);
      z[gm * 64 + maskoff + j] = y;
      Anext[gm * AK + j] = (f16)y;   // next layer's unmasked input
      sp[r] += s;
    }
  }
#pragma unroll
  for (int r = 0; r < 4; ++r) {
    float v = sp[r];
    v += __shfl_xor(v, 1);
    v += __shfl_xor(v, 2);
    v += __shfl_xor(v, 4);
    v += __shfl_xor(v, 8);
    if (c15 == 0) {
      const long gm = rowStart + wm + quad * 4 + r;
      log_det[gm] += v;   // only this thread touches this row this layer
    }
  }
}

// ---------------------------------------------------------------------------
extern "C" void kernel_launch(void* const* d_in, const int* in_sizes, int n_in,
                              void* d_out, int out_size, void* d_ws, size_t ws_size,
                              hipStream_t stream) {
  (void)in_sizes; (void)n_in; (void)out_size; (void)ws_size;
  const float* T    = (const float*)d_in[0];
  const float* cond = (const float*)d_in[1];
  const float* W1   = (const float*)d_in[2];
  const float* b1   = (const float*)d_in[3];
  const float* W2   = (const float*)d_in[4];
  const float* b2   = (const float*)d_in[5];
  const float* W3   = (const float*)d_in[6];
  const float* b3   = (const float*)d_in[7];

  float* z  = (float*)d_out;                 // B x 64 working state = output
  float* ld = z + (size_t)NB * 64;           // B log_det

  f16* A   = (f16*)d_ws;                     // B x 160
  f16* X1  = A   + (size_t)NB * AK;          // B x 1024
  f16* X2  = X1  + (size_t)NB * HID;         // B x 1024
  f16* W1t = X2  + (size_t)NB * HID;         // 6 x 1024 x 160
  f16* W2t = W1t + (size_t)6 * 1024 * 160;   // 6 x 1024 x 1024
  f16* W3t = W2t + ((size_t)6 << 20);        // 6 x 64 x 1024

  prep_all<<<3968, 256, 0, stream>>>(T, cond, W1, W2, W3,
                                     z, ld, A, W1t, W2t, W3t);

  const int g12 = (NB / 128) * (HID / 128);  // 2048 blocks
  for (int l = 0; l < LAYERS; ++l) {
    gemm1_full<<<g12, 256, 0, stream>>>(A, W1t + (size_t)l * 1024 * AK,
                                        b1 + l * 1024, X1);
    gemm12<<<g12, 256, 0, stream>>>(X1, HID, W2t + ((size_t)l << 20),
                                    b2 + l * 1024, X2);
    const int maskoff = (l & 1) ? 32 : 0;
    gemm3_coupling<<<NB / 64, 256, 0, stream>>>(X2, W3t + (size_t)l * 64 * 1024,
                                                b3 + l * 64, z, ld, A, maskoff);
  }
}